// Round 7
// baseline (328.729 us; speedup 1.0000x reference)
//
#include <hip/hip_runtime.h>
#include <cmath>

#define NQ 16
#define NT 8

typedef float f32x4 __attribute__((ext_vector_type(4)));

// order-preserving float->u32 (total order, -inf..+inf ascending)
__device__ __forceinline__ unsigned ordf(float x) {
    unsigned u = __float_as_uint(x);
    return u ^ ((unsigned)((int)u >> 31) | 0x80000000u);
}
// inverse of ordf; k=0xFFFFFFFF (empty sentinel) maps to NaN, which makes all
// ordered float compares false -> empty/singleton groups never trigger slow path
__device__ __forceinline__ float unordf(unsigned k) {
    unsigned m = (~(unsigned)((int)k >> 31)) | 0x80000000u;
    return __uint_as_float(k ^ m);
}
__device__ __forceinline__ unsigned umin2(unsigned a, unsigned b) { return a < b ? a : b; }
__device__ __forceinline__ unsigned umax2(unsigned a, unsigned b) { return a > b ? a : b; }

// Exact reference-parity path (rare): double-exp sigmoid, exact float dedup.
// ind[] from the fast path is already exact (argmin is computed in exact f32).
__device__ __noinline__ unsigned exact_mask(
    const float* __restrict__ pred_logits,
    const float* __restrict__ pred_disp,
    const float* __restrict__ targets,
    size_t b, const int* ind)
{
    float tg[NT];
#pragma unroll
    for (int t = 0; t < NT; ++t) {
        float v = targets[b * NT + t];
        tg[t] = (v == 0.0f) ? 1000000.0f : v;
    }
    float C[NQ];
#pragma unroll
    for (int n = 0; n < NQ; ++n) {
        float d = pred_disp[b * NQ + n];
        float best = fabsf(d - tg[0]);
#pragma unroll
        for (int t = 1; t < NT; ++t) best = fminf(best, fabsf(d - tg[t]));
        float sig = (float)(1.0 / (1.0 + exp(-(double)pred_logits[b * NQ + n])));
        C[n] = (-sig) + best;               // same op order as reference
    }
    unsigned mask = 0u;
#pragma unroll
    for (int t = 0; t < NT; ++t) {
        int w = 31;
        float bc = 3.0e38f;
#pragma unroll
        for (int n = 0; n < NQ; ++n) {
            bool upd = (ind[n] == t) && (C[n] < bc);   // strict <: first query wins
            bc = upd ? C[n] : bc;
            w  = upd ? n : w;
        }
        mask |= (1u << w);
    }
    return mask;
}

// One thread per TWO rows. labels[q]=1 iff q is the lexicographic argmin of
// (C,q) among queries sharing its matched target id. Dedup runs on u32 keys
// (ord(C) with low 5 bits replaced by query id) -> one v_min_u32 chain per
// target yields winner AND stable tie-break. Scale-aware gap guard routes
// precision-sensitive rows to the exact path.
__global__ __launch_bounds__(256, 4) void nearest_matcher_kernel(
    const float* __restrict__ pred_logits,
    const float* __restrict__ pred_disp,
    const float* __restrict__ targets,
    float* __restrict__ out_idx,
    float* __restrict__ out_lab,
    int B)
{
    size_t tid = (size_t)blockIdx.x * blockDim.x + threadIdx.x;

#pragma unroll
    for (int r = 0; r < 2; ++r) {
        size_t b = 2 * tid + r;
        if (b >= (size_t)B) continue;

        // ---- targets, exact zeros -> sentinel ----
        float tg[NT];
        {
            const f32x4* tp = (const f32x4*)(targets + b * NT);
            f32x4 t0 = tp[0], t1 = tp[1];
            tg[0]=t0.x; tg[1]=t0.y; tg[2]=t0.z; tg[3]=t0.w;
            tg[4]=t1.x; tg[5]=t1.y; tg[6]=t1.z; tg[7]=t1.w;
#pragma unroll
            for (int t = 0; t < NT; ++t) tg[t] = (tg[t] == 0.0f) ? 1000000.0f : tg[t];
        }

        // ---- exact argmin over targets (strict <, first occurrence) + fast C ----
        int      ind[NQ];
        unsigned qk[NQ];
        const f32x4* dp = (const f32x4*)(pred_disp   + b * NQ);
        const f32x4* lp = (const f32x4*)(pred_logits + b * NQ);
#pragma unroll
        for (int k = 0; k < 4; ++k) {
            f32x4 d4 = dp[k];
            f32x4 l4 = lp[k];
            float dv[4] = {d4.x, d4.y, d4.z, d4.w};
            float lv[4] = {l4.x, l4.y, l4.z, l4.w};
#pragma unroll
            for (int j = 0; j < 4; ++j) {
                int n = 4 * k + j;
                float d = dv[j];
                float best = fabsf(d - tg[0]);
                int bi = 0;
#pragma unroll
                for (int t = 1; t < NT; ++t) {
                    float e = fabsf(d - tg[t]);
                    if (e < best) { best = e; bi = t; }   // exact, matches reference
                }
                ind[n] = bi;
                float sig = __builtin_amdgcn_rcpf(1.0f + __expf(-lv[j]));
                float C = best - sig;
                qk[n] = (ordf(C) & ~31u) | (unsigned)n;   // key: C order + query id
            }
        }

        // ---- per-target winner via u32 min; best/2nd-best for the guard ----
        unsigned mask = 0u;
        bool need_slow = false;
#pragma unroll
        for (int t = 0; t < NT; ++t) {
            unsigned bc = 0xFFFFFFFFu, bc2 = 0xFFFFFFFFu;
#pragma unroll
            for (int n = 0; n < NQ; ++n) {
                unsigned x = (ind[n] == t) ? qk[n] : 0xFFFFFFFFu;
                unsigned hi = umax2(bc, x);
                bc  = umin2(bc, x);
                bc2 = umin2(bc2, hi);
            }
            // guard in float domain; empty/singleton give NaN -> compare false
            float bcf  = unordf(bc);
            float bc2f = unordf(bc2);
            float thr  = fmaf(fabsf(bcf), 1.6e-5f, 2.0e-4f);  // covers sigmoid+packing err
            need_slow = need_slow || ((bc2f - bcf) < thr);
            mask |= (1u << (bc & 31u));   // empty -> bit 31, ignored by label read
        }

        if (__builtin_expect(need_slow, 0))
            mask = exact_mask(pred_logits, pred_disp, targets, b, ind);

        // ---- emit ----
        f32x4* po = (f32x4*)(out_idx + b * NQ);
        f32x4* pl = (f32x4*)(out_lab + b * NQ);
#pragma unroll
        for (int k = 0; k < 4; ++k) {
            f32x4 oi4, ol4;
            oi4.x = (float)ind[4*k+0]; oi4.y = (float)ind[4*k+1];
            oi4.z = (float)ind[4*k+2]; oi4.w = (float)ind[4*k+3];
            ol4.x = (float)((mask >> (4*k+0)) & 1u);
            ol4.y = (float)((mask >> (4*k+1)) & 1u);
            ol4.z = (float)((mask >> (4*k+2)) & 1u);
            ol4.w = (float)((mask >> (4*k+3)) & 1u);
            po[k] = oi4;
            pl[k] = ol4;
        }
    }
}

extern "C" void kernel_launch(void* const* d_in, const int* in_sizes, int n_in,
                              void* d_out, int out_size, void* d_ws, size_t ws_size,
                              hipStream_t stream) {
    const float* pred_logits = (const float*)d_in[0];
    const float* pred_disp   = (const float*)d_in[1];
    const float* targets     = (const float*)d_in[2];

    int B = in_sizes[0] / NQ;

    float* out_idx = (float*)d_out;              // indices [B, NQ] flat, first
    float* out_lab = out_idx + (size_t)B * NQ;   // labels  [B, NQ] flat, second

    const int threads = 256;
    const int rows_per_block = threads * 2;
    const int blocks = (B + rows_per_block - 1) / rows_per_block;
    hipLaunchKernelGGL(nearest_matcher_kernel, dim3(blocks), dim3(threads), 0, stream,
                       pred_logits, pred_disp, targets, out_idx, out_lab, B);
}

// Round 8
// 252.271 us; speedup vs baseline: 1.3031x; 1.3031x over previous
//
#include <hip/hip_runtime.h>
#include <cmath>

#define NQ 16
#define NT 8

typedef float f32x4 __attribute__((ext_vector_type(4)));

// order-preserving float->u32 (total order ascending)
__device__ __forceinline__ unsigned ordf(float x) {
    unsigned u = __float_as_uint(x);
    return u ^ ((unsigned)((int)u >> 31) | 0x80000000u);
}
// inverse; 0xFFFFFFFF (empty sentinel) -> NaN so ordered compares are false
__device__ __forceinline__ float unordf(unsigned k) {
    unsigned m = (~(unsigned)((int)k >> 31)) | 0x80000000u;
    return __uint_as_float(k ^ m);
}
__device__ __forceinline__ unsigned umin2(unsigned a, unsigned b) { return a < b ? a : b; }
__device__ __forceinline__ unsigned umax2(unsigned a, unsigned b) { return a > b ? a : b; }

// Exact reference-parity path (rare): recompute the whole row with the
// correctly-rounded double-exp sigmoid and exact float dedup (validated
// bit-exact vs reference in R1/R3/R6/R7, absmax 0.0).
__device__ __noinline__ unsigned exact_mask(
    const float* __restrict__ pred_logits,
    const float* __restrict__ pred_disp,
    const float* __restrict__ targets,
    size_t b)
{
    float tg[NT];
#pragma unroll
    for (int t = 0; t < NT; ++t) {
        float v = targets[b * NT + t];
        tg[t] = (v == 0.0f) ? 1000000.0f : v;
    }
    float C[NQ];
    int   ind[NQ];
#pragma unroll
    for (int n = 0; n < NQ; ++n) {
        float d = pred_disp[b * NQ + n];
        float best = fabsf(d - tg[0]);
        int bi = 0;
#pragma unroll
        for (int t = 1; t < NT; ++t) {
            float e = fabsf(d - tg[t]);
            if (e < best) { best = e; bi = t; }   // strict <: first target wins
        }
        float sig = (float)(1.0 / (1.0 + exp(-(double)pred_logits[b * NQ + n])));
        C[n] = (-sig) + best;                     // same op order as reference
        ind[n] = bi;
    }
    unsigned mask = 0u;
#pragma unroll
    for (int t = 0; t < NT; ++t) {
        int w = 31;
        float bc = 3.0e38f;
#pragma unroll
        for (int n = 0; n < NQ; ++n) {
            bool upd = (ind[n] == t) && (C[n] < bc);  // strict <: first query wins
            bc = upd ? C[n] : bc;
            w  = upd ? n : w;
        }
        mask |= (1u << w);
    }
    return mask;
}

// FOUR lanes per row: lane j of a quad owns queries 4j..4j+3, so every global
// load/store is 16 B/lane contiguous (16 cache lines per wave instruction vs
// 64 for the row-per-thread layout). Targets are shared across the quad via
// __shfl_xor; per-target best/2nd-best u32 keys reduce across the quad with
// the min/max-pair merge. Scale-aware gap guard routes precision-sensitive
// rows (whole quad together) to the exact path.
__global__ __launch_bounds__(256) void nearest_matcher_kernel(
    const float* __restrict__ pred_logits,
    const float* __restrict__ pred_disp,
    const float* __restrict__ targets,
    float* __restrict__ out_idx,
    float* __restrict__ out_lab,
    int B)
{
    const size_t gid = (size_t)blockIdx.x * blockDim.x + threadIdx.x;
    const size_t b   = gid >> 2;          // row
    const int    j   = (int)(gid & 3);    // lane-in-quad: owns queries 4j..4j+3
    if (b >= (size_t)B) return;

    const float BIGF = 1000000.0f;

    // ---- coalesced loads: 16 B/lane, consecutive lanes consecutive addrs ----
    f32x4 d4 = ((const f32x4*)pred_disp)[gid];
    f32x4 l4 = ((const f32x4*)pred_logits)[gid];
    f32x4 t4 = ((const f32x4*)targets)[b * 2 + (size_t)(j & 1)];  // half (j&1)

    // sentinel-replace my half, then swap halves across the quad (j ^ 1)
    {
        float tv[4] = {t4.x, t4.y, t4.z, t4.w};
#pragma unroll
        for (int i = 0; i < 4; ++i) tv[i] = (tv[i] == 0.0f) ? BIGF : tv[i];
        t4.x = tv[0]; t4.y = tv[1]; t4.z = tv[2]; t4.w = tv[3];
    }
    f32x4 o4;
    o4.x = __shfl_xor(t4.x, 1, 4);
    o4.y = __shfl_xor(t4.y, 1, 4);
    o4.z = __shfl_xor(t4.z, 1, 4);
    o4.w = __shfl_xor(t4.w, 1, 4);

    float tg[NT];
    if ((j & 1) == 0) {
        tg[0]=t4.x; tg[1]=t4.y; tg[2]=t4.z; tg[3]=t4.w;
        tg[4]=o4.x; tg[5]=o4.y; tg[6]=o4.z; tg[7]=o4.w;
    } else {
        tg[0]=o4.x; tg[1]=o4.y; tg[2]=o4.z; tg[3]=o4.w;
        tg[4]=t4.x; tg[5]=t4.y; tg[6]=t4.z; tg[7]=t4.w;
    }

    // ---- my 4 queries: exact argmin over 8 targets + fast-sigmoid key ----
    int      ind[4];
    unsigned qk[4];
    {
        float dv[4] = {d4.x, d4.y, d4.z, d4.w};
        float lv[4] = {l4.x, l4.y, l4.z, l4.w};
#pragma unroll
        for (int i = 0; i < 4; ++i) {
            float d = dv[i];
            float best = fabsf(d - tg[0]);
            int bi = 0;
#pragma unroll
            for (int t = 1; t < NT; ++t) {
                float e = fabsf(d - tg[t]);
                if (e < best) { best = e; bi = t; }   // exact: matches reference
            }
            ind[i] = bi;
            float sig = __builtin_amdgcn_rcpf(1.0f + __expf(-lv[i]));
            float C = best - sig;
            int n = 4 * j + i;                        // global query id
            qk[i] = (ordf(C) & ~31u) | (unsigned)n;   // key: C order + query id
        }
    }

    // ---- per-target (best, 2nd-best) keys: local over 4, reduce over quad ----
    unsigned mask = 0u;
    bool need_slow = false;
#pragma unroll
    for (int t = 0; t < NT; ++t) {
        unsigned bc = 0xFFFFFFFFu, bc2 = 0xFFFFFFFFu;
#pragma unroll
        for (int i = 0; i < 4; ++i) {
            unsigned x = (ind[i] == t) ? qk[i] : 0xFFFFFFFFu;
            unsigned hi = umax2(bc, x);
            bc  = umin2(bc, x);
            bc2 = umin2(bc2, hi);
        }
#pragma unroll
        for (int r = 1; r <= 2; r <<= 1) {
            unsigned ob  = __shfl_xor(bc,  r, 4);
            unsigned ob2 = __shfl_xor(bc2, r, 4);
            unsigned hi  = umax2(bc, ob);
            bc  = umin2(bc, ob);
            bc2 = umin2(umin2(bc2, ob2), hi);
        }
        // guard in float domain; empty/singleton -> NaN -> compare false.
        // thr covers fast-sigmoid error + 5-bit key clearing at all C scales.
        float bcf  = unordf(bc);
        float bc2f = unordf(bc2);
        float thr  = fmaf(fabsf(bcf), 1.6e-5f, 2.0e-4f);
        need_slow = need_slow || ((bc2f - bcf) < thr);
        mask |= (1u << (bc & 31u));       // empty -> bit 31, ignored below
    }

    // whole quad agrees (reduced values identical) -> no intra-quad divergence
    if (__builtin_expect(need_slow, 0))
        mask = exact_mask(pred_logits, pred_disp, targets, b);

    // ---- emit my 4 queries: 16 B/lane contiguous ----
    f32x4 oi, ol;
    oi.x = (float)ind[0]; oi.y = (float)ind[1];
    oi.z = (float)ind[2]; oi.w = (float)ind[3];
    ol.x = (float)((mask >> (4 * j + 0)) & 1u);
    ol.y = (float)((mask >> (4 * j + 1)) & 1u);
    ol.z = (float)((mask >> (4 * j + 2)) & 1u);
    ol.w = (float)((mask >> (4 * j + 3)) & 1u);
    ((f32x4*)out_idx)[gid] = oi;
    ((f32x4*)out_lab)[gid] = ol;
}

extern "C" void kernel_launch(void* const* d_in, const int* in_sizes, int n_in,
                              void* d_out, int out_size, void* d_ws, size_t ws_size,
                              hipStream_t stream) {
    const float* pred_logits = (const float*)d_in[0];
    const float* pred_disp   = (const float*)d_in[1];
    const float* targets     = (const float*)d_in[2];

    int B = in_sizes[0] / NQ;

    float* out_idx = (float*)d_out;              // indices [B, NQ] flat, first
    float* out_lab = out_idx + (size_t)B * NQ;   // labels  [B, NQ] flat, second

    const int threads = 256;
    const size_t total = (size_t)B * 4;          // 4 lanes per row
    const int blocks = (int)((total + threads - 1) / threads);
    hipLaunchKernelGGL(nearest_matcher_kernel, dim3(blocks), dim3(threads), 0, stream,
                       pred_logits, pred_disp, targets, out_idx, out_lab, B);
}